// Round 4
// baseline (1045.664 us; speedup 1.0000x reference)
//
#include <hip/hip_runtime.h>
#include <hip/hip_bf16.h>

#define B_ 4
#define N_ 8192
#define M_ 2048
#define K_ 8

typedef __bf16 bf16x8 __attribute__((ext_vector_type(8)));
typedef __bf16 bf16x4 __attribute__((ext_vector_type(4)));
typedef float  floatx4 __attribute__((ext_vector_type(4)));

// Dual-dtype scalar load: element i of array p, fp32 or bf16 per flag.
__device__ __forceinline__ float ldf(const void* p, int i, bool f32) {
  return f32 ? ((const float*)p)[i] : (float)((const __bf16*)p)[i];
}
// Dual-dtype 8-element W-fragment load (i must be 8-elem aligned in-array).
__device__ __forceinline__ bf16x8 ldw8(const void* p, int i, bool f32) {
  bf16x8 r;
  if (f32) {
    const floatx4* f = (const floatx4*)((const float*)p + i);
    floatx4 a = f[0], b = f[1];
    #pragma unroll
    for (int j = 0; j < 4; j++) { r[j] = (__bf16)a[j]; r[4 + j] = (__bf16)b[j]; }
  } else {
    r = *(const bf16x8*)((const __bf16*)p + i);
  }
  return r;
}

// ---------------------------------------------------------------------------
// One MFMA layer: wave computes MT*16 rows x cols [c0, c0+32).
// X in LDS (row-major bf16, xstride elems). W in global [outcol][k] (dual
// dtype). KMAX>0 -> guarded scalar W loads (for the stride-259 w1_0).
// Fragment maps (gfx950): A[m=lane&15][k=quad*8+j], B[n=lane&15][k=quad*8+j],
// D[row=quad*4+reg][col=lane&15].
// ---------------------------------------------------------------------------
template <int KSTEPS, int WSTRIDE, int KMAX, int MT>
__device__ __forceinline__ void mfma_layer(
    const __bf16* X, int xstride,
    const void* W, bool f32,
    const void* sv, const void* bv,
    __bf16* Y, int ystride, int ycolbase,
    int c0, int lane)
{
  const int lrow = lane & 15, quad = lane >> 4;
  floatx4 acc[MT][2];
  const floatx4 fz = {0.f, 0.f, 0.f, 0.f};
  #pragma unroll
  for (int mt = 0; mt < MT; mt++) { acc[mt][0] = fz; acc[mt][1] = fz; }

  #pragma unroll
  for (int ks = 0; ks < KSTEPS; ks++) {
    const int k = ks * 32 + quad * 8;
    bf16x8 b0, b1;
    if constexpr (KMAX > 0) {            // guarded scalar loads (w1_0, stride 259)
      #pragma unroll
      for (int j = 0; j < 8; j++) {
        const int kk = k + j;
        b0[j] = (kk < KMAX) ? (__bf16)ldf(W, (c0 + lrow) * WSTRIDE + kk, f32) : (__bf16)0.0f;
        b1[j] = (kk < KMAX) ? (__bf16)ldf(W, (c0 + 16 + lrow) * WSTRIDE + kk, f32) : (__bf16)0.0f;
      }
    } else {
      b0 = ldw8(W, (c0 + lrow) * WSTRIDE + k, f32);
      b1 = ldw8(W, (c0 + 16 + lrow) * WSTRIDE + k, f32);
    }
    #pragma unroll
    for (int mt = 0; mt < MT; mt++) {
      bf16x8 a = *(const bf16x8*)(X + (mt * 16 + lrow) * xstride + k);
      acc[mt][0] = __builtin_amdgcn_mfma_f32_16x16x32_bf16(a, b0, acc[mt][0], 0, 0, 0);
      acc[mt][1] = __builtin_amdgcn_mfma_f32_16x16x32_bf16(a, b1, acc[mt][1], 0, 0, 0);
    }
  }

  #pragma unroll
  for (int ct = 0; ct < 2; ct++) {
    const int col = c0 + ct * 16 + lrow;
    const float s = ldf(sv, col, f32);
    const float bb = ldf(bv, col, f32);
    #pragma unroll
    for (int mt = 0; mt < MT; mt++) {
      #pragma unroll
      for (int r = 0; r < 4; r++) {
        float v = acc[mt][ct][r] * s + bb;
        v = v > 0.f ? v : 0.f;
        Y[(mt * 16 + quad * 4 + r) * ystride + (col - ycolbase)] = (__bf16)v;
      }
    }
  }
}

// ---------------------------------------------------------------------------
// Fully self-contained: dtype-detect + KNN + gather + MLP1(3) + maxpool +
// concat(feature1) + MLP2. Block = 256 threads, 8 query points. Zero d_ws.
// LDS 55,296 B + 260 B (<=64 KB):
//   SH[0:37888)   = XG [64][296]  (also KNN x2s/y2s/z2s/r2s 32 KB, then
//                   Y1 = XG[0:8704 elems), Y2 = XG[8704:17408 elems))
//   SH[37888:...) = Y0 [64][136]  (later XM [16][520]: maxed|feature1)
// All aliases are barrier-guarded; every read region is written first.
// ---------------------------------------------------------------------------
__global__ __launch_bounds__(256) void fused_kernel(
    const void* __restrict__ pos1, const void* __restrict__ pos2,
    const void* __restrict__ feature1, const void* __restrict__ feature2,
    const void* __restrict__ w10, const void* __restrict__ s10, const void* __restrict__ b10,
    const void* __restrict__ w11, const void* __restrict__ s11, const void* __restrict__ b11,
    const void* __restrict__ w12, const void* __restrict__ s12, const void* __restrict__ b12,
    const void* __restrict__ w20, const void* __restrict__ s20, const void* __restrict__ b20,
    void* __restrict__ out)
{
  __shared__ __align__(16) unsigned char SH[55296];
  __shared__ int knn_idx[64];
  __shared__ int s_cnt;

  __bf16* XG = (__bf16*)SH;                 // [64][296]
  __bf16* Y0 = (__bf16*)(SH + 37888);       // [64][136]
  __bf16* Y1 = XG;
  __bf16* Y2 = XG + 64 * 136;
  __bf16* XM = Y0;                          // [16][520]
  float* x2s = (float*)SH;                  // [2048] (aliases XG, pre-gather)
  float* y2s = x2s + 2048;
  float* z2s = y2s + 2048;
  float* r2s = z2s + 2048;

  const int b = blockIdx.y;
  const int n0 = blockIdx.x * 8;
  const int tid = threadIdx.x;
  const int wave = tid >> 6, lane = tid & 63;
  const int lrow = lane & 15, quad = lane >> 4;

  // ---- 1. dtype detection: scan 2048 dwords of pos2; bf16 data has ~zero
  // half-words with exponent >= 0x90; fp32 low half-words ~44%.
  if (tid == 0) s_cnt = 0;
  __syncthreads();
  {
    const unsigned* p = (const unsigned*)pos2;
    int local = 0;
    #pragma unroll
    for (int j = 0; j < 8; j++) {
      unsigned u = p[tid + 256 * j];
      int e0 = (u >> 7) & 0xFF, e1 = (u >> 23) & 0xFF;
      local += (e0 >= 0x90) + (e1 >= 0x90);
    }
    atomicAdd(&s_cnt, local);
  }
  __syncthreads();
  const bool f32 = (s_cnt > 64);
  __syncthreads();            // s_cnt read done before any reuse of LDS

  // ---- 2. KNN: stage pos2[b] in fp32 LDS
  for (int i = tid; i < M_; i += 256) {
    float x = ldf(pos2, b * 3 * M_ + i, f32);
    float y = ldf(pos2, b * 3 * M_ + M_ + i, f32);
    float z = ldf(pos2, b * 3 * M_ + 2 * M_ + i, f32);
    x2s[i] = x; y2s[i] = y; z2s[i] = z;
    r2s[i] = __fadd_rn(__fadd_rn(__fmul_rn(x, x), __fmul_rn(y, y)), __fmul_rn(z, z));
  }
  __syncthreads();

  // 32 lanes per point; per-lane top-8 over m = l + 32*j (strict < keeps
  // earlier m on ties), then 8-round (d,idx)-lexicographic tournament.
  {
    const int p = tid >> 5, l = tid & 31;
    const int n = n0 + p;
    float x1 = ldf(pos1, b * 3 * N_ + n, f32);
    float y1 = ldf(pos1, b * 3 * N_ + N_ + n, f32);
    float z1 = ldf(pos1, b * 3 * N_ + 2 * N_ + n, f32);
    float r1 = __fadd_rn(__fadd_rn(__fmul_rn(x1, x1), __fmul_rn(y1, y1)), __fmul_rn(z1, z1));

    float bd[K_]; int bi[K_];
    #pragma unroll
    for (int j = 0; j < K_; j++) { bd[j] = 3.0e38f; bi[j] = 0x7fffffff; }

    for (int j = 0; j < M_ / 32; j++) {
      const int m = l + 32 * j;
      float dot = __fadd_rn(__fadd_rn(__fmul_rn(x1, x2s[m]), __fmul_rn(y1, y2s[m])),
                            __fmul_rn(z1, z2s[m]));
      float d = __fsub_rn(__fadd_rn(r1, r2s[m]), __fmul_rn(2.0f, dot));
      if (d < bd[K_ - 1]) {
        float cd = d; int ci = m;
        #pragma unroll
        for (int q = 0; q < K_; q++) {
          bool lt = (cd < bd[q]);
          float nd = lt ? cd : bd[q];  int ni = lt ? ci : bi[q];
          float od = lt ? bd[q] : cd;  int oi = lt ? bi[q] : ci;
          bd[q] = nd; bi[q] = ni; cd = od; ci = oi;
        }
      }
    }

    int h = 0;
    for (int r = 0; r < K_; r++) {
      float cd = 3.3e38f; int ci = 0x7fffffff;
      #pragma unroll
      for (int q = 0; q < K_; q++) if (h == q) { cd = bd[q]; ci = bi[q]; }
      const int myi = ci;
      #pragma unroll
      for (int s = 1; s < 32; s <<= 1) {
        float od = __shfl_xor(cd, s, 32);
        int   oi = __shfl_xor(ci, s, 32);
        if (od < cd || (od == cd && oi < ci)) { cd = od; ci = oi; }
      }
      if (ci == myi) h++;
      if (l == 0) knn_idx[p * K_ + r] = ci;
    }
  }
  __syncthreads();   // knn_idx visible; x2s..r2s dead -> XG reusable

  // ---- 3. gather: row r = g*8+rank gets [feature2[:,m] (256) | dpos | 0pad]
  {
    const int r = tid >> 2, q = tid & 3;
    const int g = r >> 3;
    const int m = knn_idx[r];
    #pragma unroll 8
    for (int j = 0; j < 64; j++) {
      const int c = q * 64 + j;
      XG[r * 296 + c] = (__bf16)ldf(feature2, (b * 256 + c) * M_ + m, f32);
    }
    if (q == 3) {
      bf16x8* p8 = (bf16x8*)(XG + r * 296 + 256);
      const bf16x8 bz = {};
      #pragma unroll
      for (int i = 0; i < 5; i++) p8[i] = bz;     // zero cols 256..295
      const int n = n0 + g;
      float dx = ldf(pos2, b * 3 * M_ + m, f32)          - ldf(pos1, b * 3 * N_ + n, f32);
      float dy = ldf(pos2, b * 3 * M_ + M_ + m, f32)     - ldf(pos1, b * 3 * N_ + N_ + n, f32);
      float dz = ldf(pos2, b * 3 * M_ + 2 * M_ + m, f32) - ldf(pos1, b * 3 * N_ + 2 * N_ + n, f32);
      XG[r * 296 + 256] = (__bf16)dx;
      XG[r * 296 + 257] = (__bf16)dy;
      XG[r * 296 + 258] = (__bf16)dz;
    }
  }
  __syncthreads();

  // ---- 4. MLP1
  mfma_layer<9, 259, 259, 4>(XG, 296, w10, f32, s10, b10, Y0, 136, 0, 32 * wave, lane);
  __syncthreads();
  mfma_layer<4, 128, 0, 4>(Y0, 136, w11, f32, s11, b11, Y1, 136, 0, 32 * wave, lane);
  __syncthreads();

  // stage feature1 -> XM cols 256..511 (Y0 dead after L1)
  {
    const int c = tid;
    const int base = (b * 256 + c) * N_ + n0;
    if (f32) {
      const floatx4* f = (const floatx4*)((const float*)feature1 + base);
      floatx4 v0 = f[0], v1 = f[1];
      #pragma unroll
      for (int g = 0; g < 4; g++) {
        XM[g * 520 + 256 + c] = (__bf16)v0[g];
        XM[(g + 4) * 520 + 256 + c] = (__bf16)v1[g];
      }
    } else {
      bf16x8 v = *(const bf16x8*)((const __bf16*)feature1 + base);
      #pragma unroll
      for (int g = 0; g < 8; g++) XM[g * 520 + 256 + c] = v[g];
    }
  }

  // L2 (128->256) in two 128-col passes, each maxpooled over k into XM
  #pragma unroll
  for (int p = 0; p < 2; p++) {
    mfma_layer<4, 128, 0, 4>(Y1, 136, w12, f32, s12, b12, Y2, 136, 128 * p,
                             128 * p + 32 * wave, lane);
    __syncthreads();
    #pragma unroll
    for (int ii = 0; ii < 4; ii++) {
      int o = tid + 256 * ii;            // 8 g x 128 c
      int c = o & 127, g = o >> 7;
      float mx = (float)Y2[(g * 8) * 136 + c];
      #pragma unroll
      for (int k = 1; k < 8; k++) {
        float v = (float)Y2[(g * 8 + k) * 136 + c];
        mx = v > mx ? v : mx;
      }
      XM[g * 520 + 128 * p + c] = (__bf16)mx;
    }
    __syncthreads();
  }

  // ---- 5. MLP2: A = XM[16][520] (rows 0..7 real; rows 8..15 stale-finite,
  // never stored — MFMA rows are independent). B = w20 [256][512].
  {
    floatx4 acc2[4];
    const floatx4 fz = {0.f, 0.f, 0.f, 0.f};
    #pragma unroll
    for (int ct = 0; ct < 4; ct++) acc2[ct] = fz;

    #pragma unroll
    for (int ks = 0; ks < 16; ks++) {
      const int k = ks * 32 + quad * 8;
      bf16x8 a = *(const bf16x8*)(XM + lrow * 520 + k);
      #pragma unroll
      for (int ct = 0; ct < 4; ct++) {
        const int col = 64 * wave + ct * 16 + lrow;
        bf16x8 bb = ldw8(w20, col * 512 + k, f32);
        acc2[ct] = __builtin_amdgcn_mfma_f32_16x16x32_bf16(a, bb, acc2[ct], 0, 0, 0);
      }
    }

    if (quad < 2) {                      // D rows 0..7 = the 8 real points
      #pragma unroll
      for (int ct = 0; ct < 4; ct++) {
        const int col = 64 * wave + ct * 16 + lrow;
        const float s = ldf(s20, col, f32);
        const float bb = ldf(b20, col, f32);
        float v[4];
        #pragma unroll
        for (int r = 0; r < 4; r++) {
          float t = acc2[ct][r] * s + bb;
          v[r] = t > 0.f ? t : 0.f;
        }
        const int base = (b * 256 + col) * N_ + n0 + quad * 4;
        if (f32) {
          floatx4 pk = {v[0], v[1], v[2], v[3]};
          *(floatx4*)((float*)out + base) = pk;
        } else {
          bf16x4 pk = {(__bf16)v[0], (__bf16)v[1], (__bf16)v[2], (__bf16)v[3]};
          *(bf16x4*)((__bf16*)out + base) = pk;
        }
      }
    }
  }
}

// ---------------------------------------------------------------------------
extern "C" void kernel_launch(void* const* d_in, const int* in_sizes, int n_in,
                              void* d_out, int out_size, void* d_ws, size_t ws_size,
                              hipStream_t stream)
{
  (void)d_ws; (void)ws_size; (void)in_sizes; (void)n_in; (void)out_size;
  fused_kernel<<<dim3(N_ / 8, B_), 256, 0, stream>>>(
      d_in[0], d_in[1], d_in[2], d_in[3],
      d_in[4], d_in[5], d_in[6],
      d_in[7], d_in[8], d_in[9],
      d_in[10], d_in[11], d_in[12],
      d_in[13], d_in[14], d_in[15],
      d_out);
}

// Round 5
// 619.195 us; speedup vs baseline: 1.6887x; 1.6887x over previous
//
#include <hip/hip_runtime.h>
#include <hip/hip_bf16.h>

#define B_ 4
#define N_ 8192
#define M_ 2048
#define K_ 8

typedef __bf16 bf16x8 __attribute__((ext_vector_type(8)));
typedef float  floatx4 __attribute__((ext_vector_type(4)));

// ---------------------------------------------------------------------------
// Cast all MLP weights fp32 -> bf16 once. w1_0 [128,259] zero-padded to
// [128,288]. Flat segments: 36864 | 16384 | 32768 | 131072 = 217088 elems.
// ---------------------------------------------------------------------------
__global__ __launch_bounds__(256) void prep_weights(
    const float* __restrict__ w10, const float* __restrict__ w11,
    const float* __restrict__ w12, const float* __restrict__ w20,
    __bf16* __restrict__ w0p, __bf16* __restrict__ w11b,
    __bf16* __restrict__ w12b, __bf16* __restrict__ w20b)
{
  int t = blockIdx.x * 256 + threadIdx.x;
  if (t < 36864) {
    int o = t / 288, c = t - o * 288;
    w0p[t] = (c < 259) ? (__bf16)w10[o * 259 + c] : (__bf16)0.0f;
  } else if (t < 53248) {
    int i = t - 36864; w11b[i] = (__bf16)w11[i];
  } else if (t < 86016) {
    int i = t - 53248; w12b[i] = (__bf16)w12[i];
  } else if (t < 217088) {
    int i = t - 86016; w20b[i] = (__bf16)w20[i];
  }
}

// ---------------------------------------------------------------------------
// [B,C,L] fp32 -> [B,L,C] bf16 transpose+cast (C,L multiples of 32)
// ---------------------------------------------------------------------------
__global__ __launch_bounds__(256) void transpose_cast(
    const float* __restrict__ in, __bf16* __restrict__ out, int C, int L)
{
  __shared__ float tile[32][33];
  const int b = blockIdx.z;
  const int c0 = blockIdx.y * 32, l0 = blockIdx.x * 32;
  const int tx = threadIdx.x & 31, ty = threadIdx.x >> 5;   // ty 0..7
  const float* src = in + (size_t)b * C * L;
  #pragma unroll
  for (int i = 0; i < 4; i++)
    tile[ty + 8 * i][tx] = src[(size_t)(c0 + ty + 8 * i) * L + l0 + tx];
  __syncthreads();
  __bf16* dst = out + (size_t)b * L * C;
  #pragma unroll
  for (int i = 0; i < 4; i++)
    dst[(size_t)(l0 + ty + 8 * i) * C + c0 + tx] = (__bf16)tile[tx][ty + 8 * i];
}

// ---------------------------------------------------------------------------
// KNN: one thread per pos1 point; pos2 batch staged in LDS (fp32).
// Exact np expanded formula (r1+r2)-2*dot, no FMA contraction; streaming
// strict-< insertion == stable top_k (equal d keeps lower index).
// ---------------------------------------------------------------------------
__global__ __launch_bounds__(256) void knn_kernel(
    const float* __restrict__ pos1, const float* __restrict__ pos2,
    int* __restrict__ idx_out)
{
  __shared__ float x2s[M_], y2s[M_], z2s[M_], r2s[M_];   // 32 KB
  const int b = blockIdx.y;
  const int t = threadIdx.x;
  const float* p2 = pos2 + b * 3 * M_;
  for (int i = t; i < M_; i += 256) {
    float x = p2[i], y = p2[M_ + i], z = p2[2 * M_ + i];
    x2s[i] = x; y2s[i] = y; z2s[i] = z;
    r2s[i] = __fadd_rn(__fadd_rn(__fmul_rn(x, x), __fmul_rn(y, y)), __fmul_rn(z, z));
  }
  __syncthreads();
  const int n = blockIdx.x * 256 + t;
  const float* p1 = pos1 + b * 3 * N_;
  float x1 = p1[n], y1 = p1[N_ + n], z1 = p1[2 * N_ + n];
  float r1 = __fadd_rn(__fadd_rn(__fmul_rn(x1, x1), __fmul_rn(y1, y1)), __fmul_rn(z1, z1));

  float bd[K_]; int bi[K_];
  #pragma unroll
  for (int j = 0; j < K_; j++) { bd[j] = 3.0e38f; bi[j] = 0; }

  for (int m = 0; m < M_; m++) {
    float dot = __fadd_rn(__fadd_rn(__fmul_rn(x1, x2s[m]), __fmul_rn(y1, y2s[m])),
                          __fmul_rn(z1, z2s[m]));
    float d = __fsub_rn(__fadd_rn(r1, r2s[m]), __fmul_rn(2.0f, dot));
    if (d < bd[K_ - 1]) {
      float cd = d; int ci = m;
      #pragma unroll
      for (int q = 0; q < K_; q++) {
        bool lt = (cd < bd[q]);
        float nd = lt ? cd : bd[q];  int ni = lt ? ci : bi[q];
        float od = lt ? bd[q] : cd;  int oi = lt ? bi[q] : ci;
        bd[q] = nd; bi[q] = ni; cd = od; ci = oi;
      }
    }
  }
  int* o = idx_out + (b * N_ + n) * K_;
  #pragma unroll
  for (int j = 0; j < K_; j++) o[j] = bi[j];
}

// ---------------------------------------------------------------------------
// One MFMA layer: wave computes MT*16 rows x cols [c0, c0+32).
// X in LDS (row-major bf16). W in global bf16 [outcol][k]. s/b fp32.
// Fragment maps (gfx950, HW-verified R4): A[m=lane&15][k=quad*8+j],
// B[n=lane&15][k=quad*8+j], D[row=quad*4+reg][col=lane&15].
// ---------------------------------------------------------------------------
template <int KSTEPS, int MT>
__device__ __forceinline__ void mfma_layer(
    const __bf16* X, int xstride,
    const __bf16* W, int wstride,
    const float* sv, const float* bv,
    __bf16* Y, int ystride, int ycolbase,
    int c0, int lane)
{
  const int lrow = lane & 15, quad = lane >> 4;
  floatx4 acc[MT][2];
  const floatx4 fz = {0.f, 0.f, 0.f, 0.f};
  #pragma unroll
  for (int mt = 0; mt < MT; mt++) { acc[mt][0] = fz; acc[mt][1] = fz; }

  #pragma unroll
  for (int ks = 0; ks < KSTEPS; ks++) {
    const int k = ks * 32 + quad * 8;
    bf16x8 b0 = *(const bf16x8*)(W + (size_t)(c0 + lrow) * wstride + k);
    bf16x8 b1 = *(const bf16x8*)(W + (size_t)(c0 + 16 + lrow) * wstride + k);
    #pragma unroll
    for (int mt = 0; mt < MT; mt++) {
      bf16x8 a = *(const bf16x8*)(X + (mt * 16 + lrow) * xstride + k);
      acc[mt][0] = __builtin_amdgcn_mfma_f32_16x16x32_bf16(a, b0, acc[mt][0], 0, 0, 0);
      acc[mt][1] = __builtin_amdgcn_mfma_f32_16x16x32_bf16(a, b1, acc[mt][1], 0, 0, 0);
    }
  }

  #pragma unroll
  for (int ct = 0; ct < 2; ct++) {
    const int col = c0 + ct * 16 + lrow;
    const float s = sv[col];
    const float bb = bv[col];
    #pragma unroll
    for (int mt = 0; mt < MT; mt++) {
      #pragma unroll
      for (int r = 0; r < 4; r++) {
        float v = acc[mt][ct][r] * s + bb;
        v = v > 0.f ? v : 0.f;
        Y[(mt * 16 + quad * 4 + r) * ystride + (col - ycolbase)] = (__bf16)v;
      }
    }
  }
}

// ---------------------------------------------------------------------------
// Gather + MLP1 (3 layers) + maxpool over K=8. 256 thr, 8 query points ->
// 64 rows. Gather is contiguous 512 B/row from pre-transposed f2t (bf16).
// LDS: XG[64][296]=37,888 B + Y0[64][136]=17,408 B = 55,296 B.
// Aliases (barrier-guarded): Y1=XG[0:8704), Y2=XG[8704:17408) elems.
// ---------------------------------------------------------------------------
__global__ __launch_bounds__(256) void mlp1_kernel(
    const float* __restrict__ pos1, const float* __restrict__ pos2,
    const int* __restrict__ idx, const __bf16* __restrict__ f2t,
    const __bf16* __restrict__ w0p, const float* __restrict__ s10, const float* __restrict__ b10,
    const __bf16* __restrict__ w11b, const float* __restrict__ s11, const float* __restrict__ b11,
    const __bf16* __restrict__ w12b, const float* __restrict__ s12, const float* __restrict__ b12,
    __bf16* __restrict__ maxed)
{
  __shared__ __bf16 XG[64 * 296];
  __shared__ __bf16 Y0[64 * 136];
  __bf16* Y1 = XG;
  __bf16* Y2 = XG + 64 * 136;

  const int b = blockIdx.y;
  const int n0 = blockIdx.x * 8;
  const int tid = threadIdx.x;
  const int wave = tid >> 6, lane = tid & 63;

  // gather: row r = g*8+rank gets [feature2[:,m] (256, bf16) | dpos | 0pad]
  {
    const int r = tid >> 2, q = tid & 3;       // 4 threads per row
    const int g = r >> 3;
    const int m = idx[(b * N_ + n0) * K_ + r];
    const bf16x8* s8 = (const bf16x8*)(f2t + ((size_t)(b * M_ + m)) * 256 + q * 64);
    bf16x8* d8 = (bf16x8*)(XG + r * 296 + q * 64);
    #pragma unroll
    for (int i = 0; i < 8; i++) d8[i] = s8[i];
    if (q == 3) {
      bf16x8* p8 = (bf16x8*)(XG + r * 296 + 256);
      const bf16x8 bz = {};
      #pragma unroll
      for (int i = 0; i < 5; i++) p8[i] = bz;  // zero cols 256..295
      const int n = n0 + g;
      float dx = pos2[b * 3 * M_ + m]          - pos1[b * 3 * N_ + n];
      float dy = pos2[b * 3 * M_ + M_ + m]     - pos1[b * 3 * N_ + N_ + n];
      float dz = pos2[b * 3 * M_ + 2 * M_ + m] - pos1[b * 3 * N_ + 2 * N_ + n];
      XG[r * 296 + 256] = (__bf16)dx;
      XG[r * 296 + 257] = (__bf16)dy;
      XG[r * 296 + 258] = (__bf16)dz;
    }
  }
  __syncthreads();

  mfma_layer<9, 4>(XG, 296, w0p, 288, s10, b10, Y0, 136, 0, 32 * wave, lane);
  __syncthreads();
  mfma_layer<4, 4>(Y0, 136, w11b, 128, s11, b11, Y1, 136, 0, 32 * wave, lane);
  __syncthreads();

  #pragma unroll
  for (int p = 0; p < 2; p++) {
    mfma_layer<4, 4>(Y1, 136, w12b, 128, s12, b12, Y2, 136, 128 * p,
                     128 * p + 32 * wave, lane);
    __syncthreads();
    #pragma unroll
    for (int ii = 0; ii < 4; ii++) {
      int o = tid + 256 * ii;              // 8 g x 128 c
      int c = o & 127, g = o >> 7;
      float mx = (float)Y2[(g * 8) * 136 + c];
      #pragma unroll
      for (int k = 1; k < 8; k++) {
        float v = (float)Y2[(g * 8 + k) * 136 + c];
        mx = v > mx ? v : mx;
      }
      maxed[((size_t)(b * N_ + n0 + g)) * 256 + 128 * p + c] = (__bf16)mx;
    }
    __syncthreads();
  }
}

// ---------------------------------------------------------------------------
// MLP2: rows = flattened (b,n), 128 rows/block. A = [maxed(256)|f1t(256)]
// both bf16 row-contiguous in global. B = w20b [256][512]. Out fp32.
// 4 waves x 32-col strips, 2 col passes.
// ---------------------------------------------------------------------------
__global__ __launch_bounds__(256) void mlp2_kernel(
    const __bf16* __restrict__ maxed, const __bf16* __restrict__ f1t,
    const __bf16* __restrict__ w20b, const float* __restrict__ s20,
    const float* __restrict__ b20, float* __restrict__ out)
{
  const int rows0 = blockIdx.x * 128;          // b*N + n
  const int b = rows0 >> 13;
  const int nbase = rows0 & (N_ - 1);
  const int tid = threadIdx.x;
  const int wave = tid >> 6, lane = tid & 63;
  const int lrow = lane & 15, quad = lane >> 4;
  const floatx4 fz = {0.f, 0.f, 0.f, 0.f};

  #pragma unroll
  for (int p = 0; p < 2; p++) {
    const int c0 = 128 * p + 32 * wave;
    floatx4 acc[8][2];
    #pragma unroll
    for (int mt = 0; mt < 8; mt++) { acc[mt][0] = fz; acc[mt][1] = fz; }

    #pragma unroll
    for (int ks = 0; ks < 16; ks++) {
      const int k = ks * 32 + quad * 8;
      bf16x8 b0 = *(const bf16x8*)(w20b + (size_t)(c0 + lrow) * 512 + k);
      bf16x8 b1 = *(const bf16x8*)(w20b + (size_t)(c0 + 16 + lrow) * 512 + k);
      const __bf16* xsrc = (ks < 8) ? maxed : f1t;
      const int kk = (ks < 8) ? k : (k - 256);
      #pragma unroll
      for (int mt = 0; mt < 8; mt++) {
        bf16x8 a = *(const bf16x8*)(xsrc + (size_t)(rows0 + mt * 16 + lrow) * 256 + kk);
        acc[mt][0] = __builtin_amdgcn_mfma_f32_16x16x32_bf16(a, b0, acc[mt][0], 0, 0, 0);
        acc[mt][1] = __builtin_amdgcn_mfma_f32_16x16x32_bf16(a, b1, acc[mt][1], 0, 0, 0);
      }
    }

    #pragma unroll
    for (int ct = 0; ct < 2; ct++) {
      const int col = c0 + ct * 16 + lrow;
      const float s = s20[col];
      const float bb = b20[col];
      #pragma unroll
      for (int mt = 0; mt < 8; mt++) {
        floatx4 pk;
        #pragma unroll
        for (int r = 0; r < 4; r++) {
          float v = acc[mt][ct][r] * s + bb;
          pk[r] = v > 0.f ? v : 0.f;
        }
        const int n = nbase + mt * 16 + quad * 4;
        *(floatx4*)(out + ((size_t)(b * 256 + col)) * N_ + n) = pk;
      }
    }
  }
}

// ---------------------------------------------------------------------------
extern "C" void kernel_launch(void* const* d_in, const int* in_sizes, int n_in,
                              void* d_out, int out_size, void* d_ws, size_t ws_size,
                              hipStream_t stream)
{
  const float* pos1     = (const float*)d_in[0];
  const float* pos2     = (const float*)d_in[1];
  const float* feature1 = (const float*)d_in[2];
  const float* feature2 = (const float*)d_in[3];
  const float* w1_0 = (const float*)d_in[4];
  const float* s1_0 = (const float*)d_in[5];
  const float* b1_0 = (const float*)d_in[6];
  const float* w1_1 = (const float*)d_in[7];
  const float* s1_1 = (const float*)d_in[8];
  const float* b1_1 = (const float*)d_in[9];
  const float* w1_2 = (const float*)d_in[10];
  const float* s1_2 = (const float*)d_in[11];
  const float* b1_2 = (const float*)d_in[12];
  const float* w2_0 = (const float*)d_in[13];
  const float* s2_0 = (const float*)d_in[14];
  const float* b2_0 = (const float*)d_in[15];

  // Workspace layout (39,231,488 B total)
  char* ws = (char*)d_ws;
  int*    idx   = (int*)(ws);                    //  1,048,576 @ 0
  __bf16* f2t   = (__bf16*)(ws + 1048576);       //  4,194,304
  __bf16* f1t   = (__bf16*)(ws + 5242880);       // 16,777,216
  __bf16* maxed = (__bf16*)(ws + 22020096);      // 16,777,216
  __bf16* w0p   = (__bf16*)(ws + 38797312);      //     73,728
  __bf16* w11b  = (__bf16*)(ws + 38871040);      //     32,768
  __bf16* w12b  = (__bf16*)(ws + 38903808);      //     65,536
  __bf16* w20b  = (__bf16*)(ws + 38969344);      //    262,144

  prep_weights<<<dim3(848), 256, 0, stream>>>(w1_0, w1_1, w1_2, w2_0,
                                              w0p, w11b, w12b, w20b);
  transpose_cast<<<dim3(M_ / 32, 8, B_), 256, 0, stream>>>(feature2, f2t, 256, M_);
  transpose_cast<<<dim3(N_ / 32, 8, B_), 256, 0, stream>>>(feature1, f1t, 256, N_);
  knn_kernel<<<dim3(N_ / 256, B_), 256, 0, stream>>>(pos1, pos2, idx);
  mlp1_kernel<<<dim3(N_ / 8, B_), 256, 0, stream>>>(
      pos1, pos2, idx, f2t, w0p, s1_0, b1_0, w11b, s1_1, b1_1, w12b, s1_2, b1_2, maxed);
  mlp2_kernel<<<dim3((B_ * N_) / 128), 256, 0, stream>>>(maxed, f1t, w20b, s2_0, b2_0,
                                                         (float*)d_out);
}

// Round 6
// 445.340 us; speedup vs baseline: 2.3480x; 1.3904x over previous
//
#include <hip/hip_runtime.h>
#include <hip/hip_bf16.h>

#define B_ 4
#define N_ 8192
#define M_ 2048
#define K_ 8

typedef __bf16 bf16x8 __attribute__((ext_vector_type(8)));
typedef __bf16 bf16x4 __attribute__((ext_vector_type(4)));
typedef float  floatx4 __attribute__((ext_vector_type(4)));

// ---------------------------------------------------------------------------
// Cast all MLP weights fp32 -> bf16 once. w1_0 [128,259] zero-padded to
// [128,288]. Flat segments: 36864 | 16384 | 32768 | 131072 = 217088 elems.
// ---------------------------------------------------------------------------
__global__ __launch_bounds__(256) void prep_weights(
    const float* __restrict__ w10, const float* __restrict__ w11,
    const float* __restrict__ w12, const float* __restrict__ w20,
    __bf16* __restrict__ w0p, __bf16* __restrict__ w11b,
    __bf16* __restrict__ w12b, __bf16* __restrict__ w20b)
{
  int t = blockIdx.x * 256 + threadIdx.x;
  if (t < 36864) {
    int o = t / 288, c = t - o * 288;
    w0p[t] = (c < 259) ? (__bf16)w10[o * 259 + c] : (__bf16)0.0f;
  } else if (t < 53248) {
    int i = t - 36864; w11b[i] = (__bf16)w11[i];
  } else if (t < 86016) {
    int i = t - 53248; w12b[i] = (__bf16)w12[i];
  } else if (t < 217088) {
    int i = t - 86016; w20b[i] = (__bf16)w20[i];
  }
}

// ---------------------------------------------------------------------------
// [B,C,L] fp32 -> [B,L,C] bf16 transpose+cast (C,L multiples of 32)
// ---------------------------------------------------------------------------
__global__ __launch_bounds__(256) void transpose_cast(
    const float* __restrict__ in, __bf16* __restrict__ out, int C, int L)
{
  __shared__ float tile[32][33];
  const int b = blockIdx.z;
  const int c0 = blockIdx.y * 32, l0 = blockIdx.x * 32;
  const int tx = threadIdx.x & 31, ty = threadIdx.x >> 5;   // ty 0..7
  const float* src = in + (size_t)b * C * L;
  #pragma unroll
  for (int i = 0; i < 4; i++)
    tile[ty + 8 * i][tx] = src[(size_t)(c0 + ty + 8 * i) * L + l0 + tx];
  __syncthreads();
  __bf16* dst = out + (size_t)b * L * C;
  #pragma unroll
  for (int i = 0; i < 4; i++)
    dst[(size_t)(l0 + ty + 8 * i) * C + c0 + tx] = (__bf16)tile[tx][ty + 8 * i];
}

// ---------------------------------------------------------------------------
// KNN v2: 64 points/block, 4 threads/point, each scanning a contiguous
// 512-candidate chunk (streaming strict-< top-8 = stable), candidates staged
// as packed float4 (x,y,z,r) -> 1 ds_read_b128 per candidate. Exact np
// formula (r1+r2)-2*dot, fp32, no FMA. Final lexicographic (d,idx) 4-way
// merge reproduces lax.top_k tie-breaking (chunks are index-ordered).
// Was latency-bound at 5.7% occupancy (343 us); now 512 blocks, b128 reads.
// ---------------------------------------------------------------------------
__global__ __launch_bounds__(256) void knn_kernel(
    const float* __restrict__ pos1, const float* __restrict__ pos2,
    int* __restrict__ idx_out)
{
  __shared__ floatx4 P[M_];        // 32 KB: (x,y,z,r) per candidate
  __shared__ float md[64][33];     // 4 sorted lists x 8 per point (+pad)
  __shared__ int   mi[64][33];
  const int b = blockIdx.y;
  const int n0 = blockIdx.x * 64;
  const int tid = threadIdx.x;

  const float* p2 = pos2 + b * 3 * M_;
  for (int i = tid; i < M_; i += 256) {
    float x = p2[i], y = p2[M_ + i], z = p2[2 * M_ + i];
    floatx4 q;
    q[0] = x; q[1] = y; q[2] = z;
    q[3] = __fadd_rn(__fadd_rn(__fmul_rn(x, x), __fmul_rn(y, y)), __fmul_rn(z, z));
    P[i] = q;
  }
  __syncthreads();

  const int p = tid >> 2, t = tid & 3;
  const int n = n0 + p;
  const float* p1 = pos1 + b * 3 * N_;
  const float x1 = p1[n], y1 = p1[N_ + n], z1 = p1[2 * N_ + n];
  const float r1 = __fadd_rn(__fadd_rn(__fmul_rn(x1, x1), __fmul_rn(y1, y1)),
                             __fmul_rn(z1, z1));

  float bd[K_]; int bi[K_];
  #pragma unroll
  for (int j = 0; j < K_; j++) { bd[j] = 3.0e38f; bi[j] = 0; }

  const int base = t * 512;
  for (int j = 0; j < 512; j += 4) {
    float d4[4];
    #pragma unroll
    for (int jj = 0; jj < 4; jj++) {
      floatx4 q = P[base + j + jj];
      float dot = __fadd_rn(__fadd_rn(__fmul_rn(x1, q[0]), __fmul_rn(y1, q[1])),
                            __fmul_rn(z1, q[2]));
      d4[jj] = __fsub_rn(__fadd_rn(r1, q[3]), __fmul_rn(2.0f, dot));
    }
    #pragma unroll
    for (int jj = 0; jj < 4; jj++) {
      float d = d4[jj];
      if (d < bd[K_ - 1]) {          // strict <: equal-d keeps earlier index
        float cd = d; int ci = base + j + jj;
        #pragma unroll
        for (int q = 0; q < K_; q++) {
          bool lt = (cd < bd[q]);
          float nd = lt ? cd : bd[q];  int ni = lt ? ci : bi[q];
          float od = lt ? bd[q] : cd;  int oi = lt ? bi[q] : ci;
          bd[q] = nd; bi[q] = ni; cd = od; ci = oi;
        }
      }
    }
  }
  #pragma unroll
  for (int r = 0; r < K_; r++) { md[p][t * 8 + r] = bd[r]; mi[p][t * 8 + r] = bi[r]; }
  __syncthreads();

  if (tid < 64) {
    int h[4] = {0, 0, 0, 0};
    int* o = idx_out + ((size_t)(b * N_ + n0 + tid)) * K_;
    for (int r = 0; r < K_; r++) {
      float bdv = 3.3e38f; int bii = 0x7fffffff; int bt = 0;
      #pragma unroll
      for (int tt = 0; tt < 4; tt++) {
        if (h[tt] < 8) {
          float dv = md[tid][tt * 8 + h[tt]];
          int   iv = mi[tid][tt * 8 + h[tt]];
          if (dv < bdv || (dv == bdv && iv < bii)) { bdv = dv; bii = iv; bt = tt; }
        }
      }
      #pragma unroll
      for (int tt = 0; tt < 4; tt++) h[tt] += (bt == tt);
      o[r] = bii;
    }
  }
}

// ---------------------------------------------------------------------------
// One MFMA layer, W-major orientation: D = Wfrag x Xfrag so D rows = out
// cols, D cols = points -> each lane's 4 acc values are 4 CONSECUTIVE out
// cols => packed ds_write_b64 epilogue + float4 scale/bias loads.
// Wave tile: PT=2 point-tiles (32 points) x WT=4 col-tiles (64 cols).
// Fragment maps (gfx950, HW-verified): A[m=lane&15][k=quad*8+j],
// B[n=lane&15][k=quad*8+j], D[row=quad*4+reg][col=lane&15].
// ---------------------------------------------------------------------------
template <int KSTEPS>
__device__ __forceinline__ void mfma_layer(
    const __bf16* X, int xstride,
    const __bf16* W, int wstride,
    const float* sv, const float* bv,
    __bf16* Y, int ystride, int ycolbase,
    int c0, int ptbase, int lane)
{
  const int lrow = lane & 15, quad = lane >> 4;
  floatx4 acc[2][4];
  const floatx4 fz = {0.f, 0.f, 0.f, 0.f};
  #pragma unroll
  for (int pt = 0; pt < 2; pt++)
    #pragma unroll
    for (int wt = 0; wt < 4; wt++) acc[pt][wt] = fz;

  #pragma unroll
  for (int ks = 0; ks < KSTEPS; ks++) {
    const int k = ks * 32 + quad * 8;
    bf16x8 wf[4], xf[2];
    #pragma unroll
    for (int wt = 0; wt < 4; wt++)
      wf[wt] = *(const bf16x8*)(W + (size_t)(c0 + wt * 16 + lrow) * wstride + k);
    #pragma unroll
    for (int pt = 0; pt < 2; pt++)
      xf[pt] = *(const bf16x8*)(X + (ptbase + pt * 16 + lrow) * xstride + k);
    #pragma unroll
    for (int pt = 0; pt < 2; pt++)
      #pragma unroll
      for (int wt = 0; wt < 4; wt++)
        acc[pt][wt] = __builtin_amdgcn_mfma_f32_16x16x32_bf16(wf[wt], xf[pt],
                                                              acc[pt][wt], 0, 0, 0);
  }

  #pragma unroll
  for (int pt = 0; pt < 2; pt++) {
    #pragma unroll
    for (int wt = 0; wt < 4; wt++) {
      const int colg = c0 + wt * 16 + quad * 4;   // 4 consecutive out cols
      floatx4 s4 = *(const floatx4*)(sv + colg);
      floatx4 b4 = *(const floatx4*)(bv + colg);
      bf16x4 pk;
      #pragma unroll
      for (int r = 0; r < 4; r++) {
        float v = acc[pt][wt][r] * s4[r] + b4[r];
        pk[r] = (__bf16)(v > 0.f ? v : 0.f);
      }
      *(bf16x4*)(Y + (ptbase + pt * 16 + lrow) * ystride + (colg - ycolbase)) = pk;
    }
  }
}

// ---------------------------------------------------------------------------
// Gather + MLP1 (3 layers) + maxpool over K=8. 256 thr, 8 query points ->
// 64 rows. Gather contiguous 512 B/row from pre-transposed f2t (bf16).
// LDS: XG[64][296]=37,888 B + Y0[64][136]=17,408 B = 55,296 B.
// Aliases (barrier-guarded): Y1=XG[0:8704), Y2=XG[8704:17408) elems.
// ---------------------------------------------------------------------------
__global__ __launch_bounds__(256) void mlp1_kernel(
    const float* __restrict__ pos1, const float* __restrict__ pos2,
    const int* __restrict__ idx, const __bf16* __restrict__ f2t,
    const __bf16* __restrict__ w0p, const float* __restrict__ s10, const float* __restrict__ b10,
    const __bf16* __restrict__ w11b, const float* __restrict__ s11, const float* __restrict__ b11,
    const __bf16* __restrict__ w12b, const float* __restrict__ s12, const float* __restrict__ b12,
    __bf16* __restrict__ maxed)
{
  __shared__ __align__(16) __bf16 XG[64 * 296];
  __shared__ __align__(16) __bf16 Y0[64 * 136];
  __bf16* Y1 = XG;
  __bf16* Y2 = XG + 64 * 136;

  const int b = blockIdx.y;
  const int n0 = blockIdx.x * 8;
  const int tid = threadIdx.x;
  const int wave = tid >> 6, lane = tid & 63;
  const int cw = wave & 1, pw = wave >> 1;

  // gather: row r = g*8+rank gets [feature2[:,m] (256, bf16) | dpos | 0pad]
  {
    const int r = tid >> 2, q = tid & 3;       // 4 threads per row
    const int g = r >> 3;
    const int m = idx[(b * N_ + n0) * K_ + r];
    const bf16x8* s8 = (const bf16x8*)(f2t + ((size_t)(b * M_ + m)) * 256 + q * 64);
    bf16x8* d8 = (bf16x8*)(XG + r * 296 + q * 64);
    #pragma unroll
    for (int i = 0; i < 8; i++) d8[i] = s8[i];
    if (q == 3) {
      bf16x8* p8 = (bf16x8*)(XG + r * 296 + 256);
      const bf16x8 bz = {};
      #pragma unroll
      for (int i = 0; i < 5; i++) p8[i] = bz;  // zero cols 256..295
      const int n = n0 + g;
      float dx = pos2[b * 3 * M_ + m]          - pos1[b * 3 * N_ + n];
      float dy = pos2[b * 3 * M_ + M_ + m]     - pos1[b * 3 * N_ + N_ + n];
      float dz = pos2[b * 3 * M_ + 2 * M_ + m] - pos1[b * 3 * N_ + 2 * N_ + n];
      XG[r * 296 + 256] = (__bf16)dx;
      XG[r * 296 + 257] = (__bf16)dy;
      XG[r * 296 + 258] = (__bf16)dz;
    }
  }
  __syncthreads();

  mfma_layer<9>(XG, 296, w0p, 288, s10, b10, Y0, 136, 0, cw * 64, pw * 32, lane);
  __syncthreads();
  mfma_layer<4>(Y0, 136, w11b, 128, s11, b11, Y1, 136, 0, cw * 64, pw * 32, lane);
  __syncthreads();

  #pragma unroll
  for (int p = 0; p < 2; p++) {
    mfma_layer<4>(Y1, 136, w12b, 128, s12, b12, Y2, 136, 128 * p,
                  128 * p + cw * 64, pw * 32, lane);
    __syncthreads();
    #pragma unroll
    for (int ii = 0; ii < 4; ii++) {
      int o = tid + 256 * ii;              // 8 g x 128 c
      int c = o & 127, g = o >> 7;
      float mx = (float)Y2[(g * 8) * 136 + c];
      #pragma unroll
      for (int k = 1; k < 8; k++) {
        float v = (float)Y2[(g * 8 + k) * 136 + c];
        mx = v > mx ? v : mx;
      }
      maxed[((size_t)(b * N_ + n0 + g)) * 256 + 128 * p + c] = (__bf16)mx;
    }
    __syncthreads();
  }
}

// ---------------------------------------------------------------------------
// MLP2: rows = flattened (b,n), 128 rows/block. A = [maxed(256)|f1t(256)]
// both bf16 row-contiguous in global. B = w20b [256][512]. Out fp32 with
// packed floatx4 stores along n. 4 waves x 32-col strips, 2 col passes.
// ---------------------------------------------------------------------------
__global__ __launch_bounds__(256) void mlp2_kernel(
    const __bf16* __restrict__ maxed, const __bf16* __restrict__ f1t,
    const __bf16* __restrict__ w20b, const float* __restrict__ s20,
    const float* __restrict__ b20, float* __restrict__ out)
{
  const int rows0 = blockIdx.x * 128;          // b*N + n
  const int b = rows0 >> 13;
  const int nbase = rows0 & (N_ - 1);
  const int tid = threadIdx.x;
  const int wave = tid >> 6, lane = tid & 63;
  const int lrow = lane & 15, quad = lane >> 4;
  const floatx4 fz = {0.f, 0.f, 0.f, 0.f};

  #pragma unroll
  for (int p = 0; p < 2; p++) {
    const int c0 = 128 * p + 32 * wave;
    floatx4 acc[8][2];
    #pragma unroll
    for (int mt = 0; mt < 8; mt++) { acc[mt][0] = fz; acc[mt][1] = fz; }

    #pragma unroll
    for (int ks = 0; ks < 16; ks++) {
      const int k = ks * 32 + quad * 8;
      bf16x8 b0 = *(const bf16x8*)(w20b + (size_t)(c0 + lrow) * 512 + k);
      bf16x8 b1 = *(const bf16x8*)(w20b + (size_t)(c0 + 16 + lrow) * 512 + k);
      const __bf16* xsrc = (ks < 8) ? maxed : f1t;
      const int kk = (ks < 8) ? k : (k - 256);
      #pragma unroll
      for (int mt = 0; mt < 8; mt++) {
        bf16x8 a = *(const bf16x8*)(xsrc + (size_t)(rows0 + mt * 16 + lrow) * 256 + kk);
        acc[mt][0] = __builtin_amdgcn_mfma_f32_16x16x32_bf16(a, b0, acc[mt][0], 0, 0, 0);
        acc[mt][1] = __builtin_amdgcn_mfma_f32_16x16x32_bf16(a, b1, acc[mt][1], 0, 0, 0);
      }
    }

    #pragma unroll
    for (int ct = 0; ct < 2; ct++) {
      const int col = c0 + ct * 16 + lrow;
      const float s = s20[col];
      const float bb = b20[col];
      #pragma unroll
      for (int mt = 0; mt < 8; mt++) {
        floatx4 pk;
        #pragma unroll
        for (int r = 0; r < 4; r++) {
          float v = acc[mt][ct][r] * s + bb;
          pk[r] = v > 0.f ? v : 0.f;
        }
        const int n = nbase + mt * 16 + quad * 4;
        *(floatx4*)(out + ((size_t)(b * 256 + col)) * N_ + n) = pk;
      }
    }
  }
}

// ---------------------------------------------------------------------------
extern "C" void kernel_launch(void* const* d_in, const int* in_sizes, int n_in,
                              void* d_out, int out_size, void* d_ws, size_t ws_size,
                              hipStream_t stream)
{
  const float* pos1     = (const float*)d_in[0];
  const float* pos2     = (const float*)d_in[1];
  const float* feature1 = (const float*)d_in[2];
  const float* feature2 = (const float*)d_in[3];
  const float* w1_0 = (const float*)d_in[4];
  const float* s1_0 = (const float*)d_in[5];
  const float* b1_0 = (const float*)d_in[6];
  const float* w1_1 = (const float*)d_in[7];
  const float* s1_1 = (const float*)d_in[8];
  const float* b1_1 = (const float*)d_in[9];
  const float* w1_2 = (const float*)d_in[10];
  const float* s1_2 = (const float*)d_in[11];
  const float* b1_2 = (const float*)d_in[12];
  const float* w2_0 = (const float*)d_in[13];
  const float* s2_0 = (const float*)d_in[14];
  const float* b2_0 = (const float*)d_in[15];

  // Workspace layout (39,231,488 B total)
  char* ws = (char*)d_ws;
  int*    idx   = (int*)(ws);                    //  1,048,576 @ 0
  __bf16* f2t   = (__bf16*)(ws + 1048576);       //  4,194,304
  __bf16* f1t   = (__bf16*)(ws + 5242880);       // 16,777,216
  __bf16* maxed = (__bf16*)(ws + 22020096);      // 16,777,216
  __bf16* w0p   = (__bf16*)(ws + 38797312);      //     73,728
  __bf16* w11b  = (__bf16*)(ws + 38871040);      //     32,768
  __bf16* w12b  = (__bf16*)(ws + 38903808);      //     65,536
  __bf16* w20b  = (__bf16*)(ws + 38969344);      //    262,144

  prep_weights<<<dim3(848), 256, 0, stream>>>(w1_0, w1_1, w1_2, w2_0,
                                              w0p, w11b, w12b, w20b);
  transpose_cast<<<dim3(M_ / 32, 8, B_), 256, 0, stream>>>(feature2, f2t, 256, M_);
  transpose_cast<<<dim3(N_ / 32, 8, B_), 256, 0, stream>>>(feature1, f1t, 256, N_);
  knn_kernel<<<dim3(N_ / 64, B_), 256, 0, stream>>>(pos1, pos2, idx);
  mlp1_kernel<<<dim3(N_ / 8, B_), 256, 0, stream>>>(
      pos1, pos2, idx, f2t, w0p, s1_0, b1_0, w11b, s1_1, b1_1, w12b, s1_2, b1_2, maxed);
  mlp2_kernel<<<dim3((B_ * N_) / 128), 256, 0, stream>>>(maxed, f1t, w20b, s2_0, b2_0,
                                                         (float*)d_out);
}

// Round 7
// 417.612 us; speedup vs baseline: 2.5039x; 1.0664x over previous
//
#include <hip/hip_runtime.h>
#include <hip/hip_bf16.h>

#define B_ 4
#define N_ 8192
#define M_ 2048
#define K_ 8

typedef __bf16 bf16x8 __attribute__((ext_vector_type(8)));
typedef __bf16 bf16x4 __attribute__((ext_vector_type(4)));
typedef float  floatx4 __attribute__((ext_vector_type(4)));

// ---------------------------------------------------------------------------
// Cast all MLP weights fp32 -> bf16 once. w1_0 [128,259] zero-padded to
// [128,288]. Flat segments: 36864 | 16384 | 32768 | 131072 = 217088 elems.
// ---------------------------------------------------------------------------
__global__ __launch_bounds__(256) void prep_weights(
    const float* __restrict__ w10, const float* __restrict__ w11,
    const float* __restrict__ w12, const float* __restrict__ w20,
    __bf16* __restrict__ w0p, __bf16* __restrict__ w11b,
    __bf16* __restrict__ w12b, __bf16* __restrict__ w20b)
{
  int t = blockIdx.x * 256 + threadIdx.x;
  if (t < 36864) {
    int o = t / 288, c = t - o * 288;
    w0p[t] = (c < 259) ? (__bf16)w10[o * 259 + c] : (__bf16)0.0f;
  } else if (t < 53248) {
    int i = t - 36864; w11b[i] = (__bf16)w11[i];
  } else if (t < 86016) {
    int i = t - 53248; w12b[i] = (__bf16)w12[i];
  } else if (t < 217088) {
    int i = t - 86016; w20b[i] = (__bf16)w20[i];
  }
}

// ---------------------------------------------------------------------------
// [B,C,L] fp32 -> [B,L,C] bf16 transpose+cast (C,L multiples of 32)
// ---------------------------------------------------------------------------
__global__ __launch_bounds__(256) void transpose_cast(
    const float* __restrict__ in, __bf16* __restrict__ out, int C, int L)
{
  __shared__ float tile[32][33];
  const int b = blockIdx.z;
  const int c0 = blockIdx.y * 32, l0 = blockIdx.x * 32;
  const int tx = threadIdx.x & 31, ty = threadIdx.x >> 5;   // ty 0..7
  const float* src = in + (size_t)b * C * L;
  #pragma unroll
  for (int i = 0; i < 4; i++)
    tile[ty + 8 * i][tx] = src[(size_t)(c0 + ty + 8 * i) * L + l0 + tx];
  __syncthreads();
  __bf16* dst = out + (size_t)b * L * C;
  #pragma unroll
  for (int i = 0; i < 4; i++)
    dst[(size_t)(l0 + ty + 8 * i) * C + c0 + tx] = (__bf16)tile[tx][ty + 8 * i];
}

// ---------------------------------------------------------------------------
// KNN: 64 points/block, 4 threads/point, each scanning a contiguous
// 512-candidate chunk (streaming strict-< top-8 = stable), candidates staged
// as packed float4 (x,y,z,r) -> 1 ds_read_b128 per candidate. Exact np
// formula (r1+r2)-2*dot, fp32, no FMA. Final lexicographic (d,idx) 4-way
// merge reproduces lax.top_k tie-breaking (chunks are index-ordered).
// ---------------------------------------------------------------------------
__global__ __launch_bounds__(256) void knn_kernel(
    const float* __restrict__ pos1, const float* __restrict__ pos2,
    int* __restrict__ idx_out)
{
  __shared__ floatx4 P[M_];        // 32 KB: (x,y,z,r) per candidate
  __shared__ float md[64][33];     // 4 sorted lists x 8 per point (+pad)
  __shared__ int   mi[64][33];
  const int b = blockIdx.y;
  const int n0 = blockIdx.x * 64;
  const int tid = threadIdx.x;

  const float* p2 = pos2 + b * 3 * M_;
  for (int i = tid; i < M_; i += 256) {
    float x = p2[i], y = p2[M_ + i], z = p2[2 * M_ + i];
    floatx4 q;
    q[0] = x; q[1] = y; q[2] = z;
    q[3] = __fadd_rn(__fadd_rn(__fmul_rn(x, x), __fmul_rn(y, y)), __fmul_rn(z, z));
    P[i] = q;
  }
  __syncthreads();

  const int p = tid >> 2, t = tid & 3;
  const int n = n0 + p;
  const float* p1 = pos1 + b * 3 * N_;
  const float x1 = p1[n], y1 = p1[N_ + n], z1 = p1[2 * N_ + n];
  const float r1 = __fadd_rn(__fadd_rn(__fmul_rn(x1, x1), __fmul_rn(y1, y1)),
                             __fmul_rn(z1, z1));

  float bd[K_]; int bi[K_];
  #pragma unroll
  for (int j = 0; j < K_; j++) { bd[j] = 3.0e38f; bi[j] = 0; }

  const int base = t * 512;
  for (int j = 0; j < 512; j += 4) {
    float d4[4];
    #pragma unroll
    for (int jj = 0; jj < 4; jj++) {
      floatx4 q = P[base + j + jj];
      float dot = __fadd_rn(__fadd_rn(__fmul_rn(x1, q[0]), __fmul_rn(y1, q[1])),
                            __fmul_rn(z1, q[2]));
      d4[jj] = __fsub_rn(__fadd_rn(r1, q[3]), __fmul_rn(2.0f, dot));
    }
    #pragma unroll
    for (int jj = 0; jj < 4; jj++) {
      float d = d4[jj];
      if (d < bd[K_ - 1]) {          // strict <: equal-d keeps earlier index
        float cd = d; int ci = base + j + jj;
        #pragma unroll
        for (int q = 0; q < K_; q++) {
          bool lt = (cd < bd[q]);
          float nd = lt ? cd : bd[q];  int ni = lt ? ci : bi[q];
          float od = lt ? bd[q] : cd;  int oi = lt ? bi[q] : ci;
          bd[q] = nd; bi[q] = ni; cd = od; ci = oi;
        }
      }
    }
  }
  #pragma unroll
  for (int r = 0; r < K_; r++) { md[p][t * 8 + r] = bd[r]; mi[p][t * 8 + r] = bi[r]; }
  __syncthreads();

  if (tid < 64) {
    int h[4] = {0, 0, 0, 0};
    int* o = idx_out + ((size_t)(b * N_ + n0 + tid)) * K_;
    for (int r = 0; r < K_; r++) {
      float bdv = 3.3e38f; int bii = 0x7fffffff; int bt = 0;
      #pragma unroll
      for (int tt = 0; tt < 4; tt++) {
        if (h[tt] < 8) {
          float dv = md[tid][tt * 8 + h[tt]];
          int   iv = mi[tid][tt * 8 + h[tt]];
          if (dv < bdv || (dv == bdv && iv < bii)) { bdv = dv; bii = iv; bt = tt; }
        }
      }
      #pragma unroll
      for (int tt = 0; tt < 4; tt++) h[tt] += (bt == tt);
      o[r] = bii;
    }
  }
}

// ---------------------------------------------------------------------------
// LDS-input MFMA layer, W-major: D = Wfrag x Xfrag (D rows = out cols,
// D cols = points). Wave tile: PT=4 (all 64 rows) x WT=2 (32 cols) so each
// weight fragment is read ONCE per block. Packed bf16x4 epilogue.
// Fragment maps (gfx950, HW-verified): A[m=lane&15][k=quad*8+j],
// B[n=lane&15][k=quad*8+j], D[row=quad*4+reg][col=lane&15].
// ---------------------------------------------------------------------------
template <int KSTEPS>
__device__ __forceinline__ void mfma_layer_lds(
    const __bf16* X, const __bf16* W, int wstride,
    const float* sv, const float* bv,
    __bf16* Y, int ycolbase, int c0, int lane)
{
  const int lrow = lane & 15, quad = lane >> 4;
  floatx4 acc[4][2];
  const floatx4 fz = {0.f, 0.f, 0.f, 0.f};
  #pragma unroll
  for (int pt = 0; pt < 4; pt++) { acc[pt][0] = fz; acc[pt][1] = fz; }

  #pragma unroll
  for (int ks = 0; ks < KSTEPS; ks++) {
    const int k = ks * 32 + quad * 8;
    bf16x8 wf0 = *(const bf16x8*)(W + (size_t)(c0 + lrow) * wstride + k);
    bf16x8 wf1 = *(const bf16x8*)(W + (size_t)(c0 + 16 + lrow) * wstride + k);
    #pragma unroll
    for (int pt = 0; pt < 4; pt++) {
      bf16x8 xf = *(const bf16x8*)(X + (pt * 16 + lrow) * 136 + k);
      acc[pt][0] = __builtin_amdgcn_mfma_f32_16x16x32_bf16(wf0, xf, acc[pt][0], 0, 0, 0);
      acc[pt][1] = __builtin_amdgcn_mfma_f32_16x16x32_bf16(wf1, xf, acc[pt][1], 0, 0, 0);
    }
  }

  #pragma unroll
  for (int pt = 0; pt < 4; pt++) {
    #pragma unroll
    for (int wt = 0; wt < 2; wt++) {
      const int colg = c0 + wt * 16 + quad * 4;    // 4 consecutive out cols
      floatx4 s4 = *(const floatx4*)(sv + colg);
      floatx4 b4 = *(const floatx4*)(bv + colg);
      bf16x4 pk;
      #pragma unroll
      for (int r = 0; r < 4; r++) {
        float v = acc[pt][wt][r] * s4[r] + b4[r];
        pk[r] = (__bf16)(v > 0.f ? v : 0.f);
      }
      *(bf16x4*)(Y + (pt * 16 + lrow) * 136 + (colg - ycolbase)) = pk;
    }
  }
}

// ---------------------------------------------------------------------------
// MLP1 v3: no gather stage. L0 reads B-fragments straight from f2t (global,
// 16 B/lane, pipelined against MFMA); posdiff enters via one special k-step
// from a tiny per-row LDS table. LDS = Y0+Y1 only (34.8 KB + 1.3 KB) ->
// 4 blocks/CU (was 2). Each weight fragment read once per block (PT=4/WT=2).
// L2-pass output aliases Y0 (dead after L1); barriers guard all reuse.
// ---------------------------------------------------------------------------
__global__ __launch_bounds__(256, 4) void mlp1_kernel(
    const float* __restrict__ pos1, const float* __restrict__ pos2,
    const int* __restrict__ idx, const __bf16* __restrict__ f2t,
    const __bf16* __restrict__ w0p, const float* __restrict__ s10, const float* __restrict__ b10,
    const __bf16* __restrict__ w11b, const float* __restrict__ s11, const float* __restrict__ b11,
    const __bf16* __restrict__ w12b, const float* __restrict__ s12, const float* __restrict__ b12,
    __bf16* __restrict__ maxed)
{
  __shared__ __align__(16) __bf16 Y0[64 * 136];
  __shared__ __align__(16) __bf16 Y1[64 * 136];
  __shared__ int mrow[64];
  __shared__ __align__(16) float dp[64][4];

  const int b = blockIdx.y;
  const int n0 = blockIdx.x * 8;
  const int tid = threadIdx.x;
  const int wave = tid >> 6, lane = tid & 63;
  const int lrow = lane & 15, quad = lane >> 4;
  const int c0 = 32 * wave;

  // prologue: neighbor index + posdiff per row (row r = point g, rank k)
  if (tid < 64) {
    const int r = tid, g = r >> 3;
    const int m = idx[(b * N_ + n0) * K_ + r];
    mrow[r] = m;
    const int n = n0 + g;
    dp[r][0] = pos2[b * 3 * M_ + m]          - pos1[b * 3 * N_ + n];
    dp[r][1] = pos2[b * 3 * M_ + M_ + m]     - pos1[b * 3 * N_ + N_ + n];
    dp[r][2] = pos2[b * 3 * M_ + 2 * M_ + m] - pos1[b * 3 * N_ + 2 * N_ + n];
    dp[r][3] = 0.f;
  }
  __syncthreads();

  int mreg[4];
  #pragma unroll
  for (int pt = 0; pt < 4; pt++) mreg[pt] = mrow[pt * 16 + lrow];

  // ---- L0: K=288 (256 from f2t global + posdiff step). Out -> Y0.
  {
    floatx4 acc[4][2];
    const floatx4 fz = {0.f, 0.f, 0.f, 0.f};
    #pragma unroll
    for (int pt = 0; pt < 4; pt++) { acc[pt][0] = fz; acc[pt][1] = fz; }

    #pragma unroll
    for (int ks = 0; ks < 9; ks++) {
      const int k = ks * 32 + quad * 8;
      bf16x8 wf0 = *(const bf16x8*)(w0p + (size_t)(c0 + lrow) * 288 + k);
      bf16x8 wf1 = *(const bf16x8*)(w0p + (size_t)(c0 + 16 + lrow) * 288 + k);
      bf16x8 xf[4];
      if (ks < 8) {
        #pragma unroll
        for (int pt = 0; pt < 4; pt++)
          xf[pt] = *(const bf16x8*)(f2t + ((size_t)(b * M_ + mreg[pt])) * 256 + k);
      } else {
        #pragma unroll
        for (int pt = 0; pt < 4; pt++) {
          bf16x8 v = {};
          if (quad == 0) {             // k=256..263: [dx,dy,dz,0,0,0,0,0]
            floatx4 d = *(const floatx4*)(&dp[pt * 16 + lrow][0]);
            v[0] = (__bf16)d[0]; v[1] = (__bf16)d[1]; v[2] = (__bf16)d[2];
          }
          xf[pt] = v;                  // quads 1-3: zero (w0p zero-padded too)
        }
      }
      #pragma unroll
      for (int pt = 0; pt < 4; pt++) {
        acc[pt][0] = __builtin_amdgcn_mfma_f32_16x16x32_bf16(wf0, xf[pt], acc[pt][0], 0, 0, 0);
        acc[pt][1] = __builtin_amdgcn_mfma_f32_16x16x32_bf16(wf1, xf[pt], acc[pt][1], 0, 0, 0);
      }
    }
    #pragma unroll
    for (int pt = 0; pt < 4; pt++) {
      #pragma unroll
      for (int wt = 0; wt < 2; wt++) {
        const int colg = c0 + wt * 16 + quad * 4;
        floatx4 s4 = *(const floatx4*)(s10 + colg);
        floatx4 b4 = *(const floatx4*)(b10 + colg);
        bf16x4 pk;
        #pragma unroll
        for (int r = 0; r < 4; r++) {
          float v = acc[pt][wt][r] * s4[r] + b4[r];
          pk[r] = (__bf16)(v > 0.f ? v : 0.f);
        }
        *(bf16x4*)(Y0 + (pt * 16 + lrow) * 136 + colg) = pk;
      }
    }
  }
  __syncthreads();

  // ---- L1: 128 -> 128, Y0 -> Y1
  mfma_layer_lds<4>(Y0, w11b, 128, s11, b11, Y1, 0, c0, lane);
  __syncthreads();

  // ---- L2: 128 -> 256 in two 128-col passes (out aliases Y0), maxpool K=8
  #pragma unroll
  for (int p = 0; p < 2; p++) {
    mfma_layer_lds<4>(Y1, w12b, 128, s12, b12, Y0, 128 * p, 128 * p + c0, lane);
    __syncthreads();
    #pragma unroll
    for (int ii = 0; ii < 4; ii++) {
      int o = tid + 256 * ii;              // 8 g x 128 c
      int c = o & 127, g = o >> 7;
      float mx = (float)Y0[(g * 8) * 136 + c];
      #pragma unroll
      for (int k = 1; k < 8; k++) {
        float v = (float)Y0[(g * 8 + k) * 136 + c];
        mx = v > mx ? v : mx;
      }
      maxed[((size_t)(b * N_ + n0 + g)) * 256 + 128 * p + c] = (__bf16)mx;
    }
    __syncthreads();
  }
}

// ---------------------------------------------------------------------------
// MLP2: rows = flattened (b,n), 128 rows/block. A = [maxed(256)|f1t(256)]
// both bf16 row-contiguous in global. B = w20b [256][512]. Out fp32 with
// packed floatx4 stores along n. 4 waves x 32-col strips, 2 col passes.
// ---------------------------------------------------------------------------
__global__ __launch_bounds__(256) void mlp2_kernel(
    const __bf16* __restrict__ maxed, const __bf16* __restrict__ f1t,
    const __bf16* __restrict__ w20b, const float* __restrict__ s20,
    const float* __restrict__ b20, float* __restrict__ out)
{
  const int rows0 = blockIdx.x * 128;          // b*N + n
  const int b = rows0 >> 13;
  const int nbase = rows0 & (N_ - 1);
  const int tid = threadIdx.x;
  const int wave = tid >> 6, lane = tid & 63;
  const int lrow = lane & 15, quad = lane >> 4;
  const floatx4 fz = {0.f, 0.f, 0.f, 0.f};

  #pragma unroll
  for (int p = 0; p < 2; p++) {
    const int c0 = 128 * p + 32 * wave;
    floatx4 acc[8][2];
    #pragma unroll
    for (int mt = 0; mt < 8; mt++) { acc[mt][0] = fz; acc[mt][1] = fz; }

    #pragma unroll
    for (int ks = 0; ks < 16; ks++) {
      const int k = ks * 32 + quad * 8;
      bf16x8 b0 = *(const bf16x8*)(w20b + (size_t)(c0 + lrow) * 512 + k);
      bf16x8 b1 = *(const bf16x8*)(w20b + (size_t)(c0 + 16 + lrow) * 512 + k);
      const __bf16* xsrc = (ks < 8) ? maxed : f1t;
      const int kk = (ks < 8) ? k : (k - 256);
      #pragma unroll
      for (int mt = 0; mt < 8; mt++) {
        bf16x8 a = *(const bf16x8*)(xsrc + (size_t)(rows0 + mt * 16 + lrow) * 256 + kk);
        acc[mt][0] = __builtin_amdgcn_mfma_f32_16x16x32_bf16(a, b0, acc[mt][0], 0, 0, 0);
        acc[mt][1] = __builtin_amdgcn_mfma_f32_16x16x32_bf16(a, b1, acc[mt][1], 0, 0, 0);
      }
    }

    #pragma unroll
    for (int ct = 0; ct < 2; ct++) {
      const int col = c0 + ct * 16 + lrow;
      const float s = s20[col];
      const float bb = b20[col];
      #pragma unroll
      for (int mt = 0; mt < 8; mt++) {
        floatx4 pk;
        #pragma unroll
        for (int r = 0; r < 4; r++) {
          float v = acc[mt][ct][r] * s + bb;
          pk[r] = v > 0.f ? v : 0.f;
        }
        const int n = nbase + mt * 16 + quad * 4;
        *(floatx4*)(out + ((size_t)(b * 256 + col)) * N_ + n) = pk;
      }
    }
  }
}

// ---------------------------------------------------------------------------
extern "C" void kernel_launch(void* const* d_in, const int* in_sizes, int n_in,
                              void* d_out, int out_size, void* d_ws, size_t ws_size,
                              hipStream_t stream)
{
  const float* pos1     = (const float*)d_in[0];
  const float* pos2     = (const float*)d_in[1];
  const float* feature1 = (const float*)d_in[2];
  const float* feature2 = (const float*)d_in[3];
  const float* w1_0 = (const float*)d_in[4];
  const float* s1_0 = (const float*)d_in[5];
  const float* b1_0 = (const float*)d_in[6];
  const float* w1_1 = (const float*)d_in[7];
  const float* s1_1 = (const float*)d_in[8];
  const float* b1_1 = (const float*)d_in[9];
  const float* w1_2 = (const float*)d_in[10];
  const float* s1_2 = (const float*)d_in[11];
  const float* b1_2 = (const float*)d_in[12];
  const float* w2_0 = (const float*)d_in[13];
  const float* s2_0 = (const float*)d_in[14];
  const float* b2_0 = (const float*)d_in[15];

  // Workspace layout (39,231,488 B total)
  char* ws = (char*)d_ws;
  int*    idx   = (int*)(ws);                    //  1,048,576 @ 0
  __bf16* f2t   = (__bf16*)(ws + 1048576);       //  4,194,304
  __bf16* f1t   = (__bf16*)(ws + 5242880);       // 16,777,216
  __bf16* maxed = (__bf16*)(ws + 22020096);      // 16,777,216
  __bf16* w0p   = (__bf16*)(ws + 38797312);      //     73,728
  __bf16* w11b  = (__bf16*)(ws + 38871040);      //     32,768
  __bf16* w12b  = (__bf16*)(ws + 38903808);      //     65,536
  __bf16* w20b  = (__bf16*)(ws + 38969344);      //    262,144

  prep_weights<<<dim3(848), 256, 0, stream>>>(w1_0, w1_1, w1_2, w2_0,
                                              w0p, w11b, w12b, w20b);
  transpose_cast<<<dim3(M_ / 32, 8, B_), 256, 0, stream>>>(feature2, f2t, 256, M_);
  transpose_cast<<<dim3(N_ / 32, 8, B_), 256, 0, stream>>>(feature1, f1t, 256, N_);
  knn_kernel<<<dim3(N_ / 64, B_), 256, 0, stream>>>(pos1, pos2, idx);
  mlp1_kernel<<<dim3(N_ / 8, B_), 256, 0, stream>>>(
      pos1, pos2, idx, f2t, w0p, s1_0, b1_0, w11b, s1_1, b1_1, w12b, s1_2, b1_2, maxed);
  mlp2_kernel<<<dim3((B_ * N_) / 128), 256, 0, stream>>>(maxed, f1t, w20b, s2_0, b2_0,
                                                         (float*)d_out);
}

// Round 8
// 414.484 us; speedup vs baseline: 2.5228x; 1.0075x over previous
//
#include <hip/hip_runtime.h>
#include <hip/hip_bf16.h>

#define B_ 4
#define N_ 8192
#define M_ 2048
#define K_ 8

typedef __bf16 bf16x8 __attribute__((ext_vector_type(8)));
typedef __bf16 bf16x4 __attribute__((ext_vector_type(4)));
typedef float  floatx4 __attribute__((ext_vector_type(4)));

// ---------------------------------------------------------------------------
// Cast all MLP weights fp32 -> bf16 once. w1_0 [128,259] zero-padded to
// [128,288]. Flat segments: 36864 | 16384 | 32768 | 131072 = 217088 elems.
// ---------------------------------------------------------------------------
__global__ __launch_bounds__(256) void prep_weights(
    const float* __restrict__ w10, const float* __restrict__ w11,
    const float* __restrict__ w12, const float* __restrict__ w20,
    __bf16* __restrict__ w0p, __bf16* __restrict__ w11b,
    __bf16* __restrict__ w12b, __bf16* __restrict__ w20b)
{
  int t = blockIdx.x * 256 + threadIdx.x;
  if (t < 36864) {
    int o = t / 288, c = t - o * 288;
    w0p[t] = (c < 259) ? (__bf16)w10[o * 259 + c] : (__bf16)0.0f;
  } else if (t < 53248) {
    int i = t - 36864; w11b[i] = (__bf16)w11[i];
  } else if (t < 86016) {
    int i = t - 53248; w12b[i] = (__bf16)w12[i];
  } else if (t < 217088) {
    int i = t - 86016; w20b[i] = (__bf16)w20[i];
  }
}

// ---------------------------------------------------------------------------
// [B,C,L] fp32 -> [B,L,C] bf16 transpose+cast (C,L multiples of 32)
// ---------------------------------------------------------------------------
__global__ __launch_bounds__(256) void transpose_cast(
    const float* __restrict__ in, __bf16* __restrict__ out, int C, int L)
{
  __shared__ float tile[32][33];
  const int b = blockIdx.z;
  const int c0 = blockIdx.y * 32, l0 = blockIdx.x * 32;
  const int tx = threadIdx.x & 31, ty = threadIdx.x >> 5;   // ty 0..7
  const float* src = in + (size_t)b * C * L;
  #pragma unroll
  for (int i = 0; i < 4; i++)
    tile[ty + 8 * i][tx] = src[(size_t)(c0 + ty + 8 * i) * L + l0 + tx];
  __syncthreads();
  __bf16* dst = out + (size_t)b * L * C;
  #pragma unroll
  for (int i = 0; i < 4; i++)
    dst[(size_t)(l0 + ty + 8 * i) * C + c0 + tx] = (__bf16)tile[tx][ty + 8 * i];
}

// ---------------------------------------------------------------------------
// KNN: 64 points/block, 4 threads/point, each scanning a contiguous
// 512-candidate chunk (streaming strict-< top-8 = stable), candidates staged
// as packed float4 (x,y,z,r) -> 1 ds_read_b128 per candidate. Exact np
// formula (r1+r2)-2*dot, fp32, no FMA. Final lexicographic (d,idx) 4-way
// merge reproduces lax.top_k tie-breaking (chunks are index-ordered).
// ---------------------------------------------------------------------------
__global__ __launch_bounds__(256) void knn_kernel(
    const float* __restrict__ pos1, const float* __restrict__ pos2,
    int* __restrict__ idx_out)
{
  __shared__ floatx4 P[M_];        // 32 KB: (x,y,z,r) per candidate
  __shared__ float md[64][33];     // 4 sorted lists x 8 per point (+pad)
  __shared__ int   mi[64][33];
  const int b = blockIdx.y;
  const int n0 = blockIdx.x * 64;
  const int tid = threadIdx.x;

  const float* p2 = pos2 + b * 3 * M_;
  for (int i = tid; i < M_; i += 256) {
    float x = p2[i], y = p2[M_ + i], z = p2[2 * M_ + i];
    floatx4 q;
    q[0] = x; q[1] = y; q[2] = z;
    q[3] = __fadd_rn(__fadd_rn(__fmul_rn(x, x), __fmul_rn(y, y)), __fmul_rn(z, z));
    P[i] = q;
  }
  __syncthreads();

  const int p = tid >> 2, t = tid & 3;
  const int n = n0 + p;
  const float* p1 = pos1 + b * 3 * N_;
  const float x1 = p1[n], y1 = p1[N_ + n], z1 = p1[2 * N_ + n];
  const float r1 = __fadd_rn(__fadd_rn(__fmul_rn(x1, x1), __fmul_rn(y1, y1)),
                             __fmul_rn(z1, z1));

  float bd[K_]; int bi[K_];
  #pragma unroll
  for (int j = 0; j < K_; j++) { bd[j] = 3.0e38f; bi[j] = 0; }

  const int base = t * 512;
  for (int j = 0; j < 512; j += 4) {
    float d4[4];
    #pragma unroll
    for (int jj = 0; jj < 4; jj++) {
      floatx4 q = P[base + j + jj];
      float dot = __fadd_rn(__fadd_rn(__fmul_rn(x1, q[0]), __fmul_rn(y1, q[1])),
                            __fmul_rn(z1, q[2]));
      d4[jj] = __fsub_rn(__fadd_rn(r1, q[3]), __fmul_rn(2.0f, dot));
    }
    #pragma unroll
    for (int jj = 0; jj < 4; jj++) {
      float d = d4[jj];
      if (d < bd[K_ - 1]) {          // strict <: equal-d keeps earlier index
        float cd = d; int ci = base + j + jj;
        #pragma unroll
        for (int q = 0; q < K_; q++) {
          bool lt = (cd < bd[q]);
          float nd = lt ? cd : bd[q];  int ni = lt ? ci : bi[q];
          float od = lt ? bd[q] : cd;  int oi = lt ? bi[q] : ci;
          bd[q] = nd; bi[q] = ni; cd = od; ci = oi;
        }
      }
    }
  }
  #pragma unroll
  for (int r = 0; r < K_; r++) { md[p][t * 8 + r] = bd[r]; mi[p][t * 8 + r] = bi[r]; }
  __syncthreads();

  if (tid < 64) {
    int h[4] = {0, 0, 0, 0};
    int* o = idx_out + ((size_t)(b * N_ + n0 + tid)) * K_;
    for (int r = 0; r < K_; r++) {
      float bdv = 3.3e38f; int bii = 0x7fffffff; int bt = 0;
      #pragma unroll
      for (int tt = 0; tt < 4; tt++) {
        if (h[tt] < 8) {
          float dv = md[tid][tt * 8 + h[tt]];
          int   iv = mi[tid][tt * 8 + h[tt]];
          if (dv < bdv || (dv == bdv && iv < bii)) { bdv = dv; bii = iv; bt = tt; }
        }
      }
      #pragma unroll
      for (int tt = 0; tt < 4; tt++) h[tt] += (bt == tt);
      o[r] = bii;
    }
  }
}

// ---------------------------------------------------------------------------
// LDS-input MFMA layer with next-kstep register prefetch (weights global,
// X from LDS). W-major: D rows = out cols, D cols = points. PT=4 x WT=2,
// weights read once per block. Packed bf16x4 epilogue.
// Fragment maps (gfx950, HW-verified): A[m=lane&15][k=quad*8+j],
// B[n=lane&15][k=quad*8+j], D[row=quad*4+reg][col=lane&15].
// ---------------------------------------------------------------------------
template <int KSTEPS>
__device__ __forceinline__ void mfma_layer_lds(
    const __bf16* X, const __bf16* W, int wstride,
    const float* sv, const float* bv,
    __bf16* Y, int ycolbase, int c0, int lane)
{
  const int lrow = lane & 15, quad = lane >> 4;
  floatx4 acc[4][2];
  const floatx4 fz = {0.f, 0.f, 0.f, 0.f};
  #pragma unroll
  for (int pt = 0; pt < 4; pt++) { acc[pt][0] = fz; acc[pt][1] = fz; }

  bf16x8 wf0 = *(const bf16x8*)(W + (size_t)(c0 + lrow) * wstride + quad * 8);
  bf16x8 wf1 = *(const bf16x8*)(W + (size_t)(c0 + 16 + lrow) * wstride + quad * 8);
  bf16x8 xf[4];
  #pragma unroll
  for (int pt = 0; pt < 4; pt++)
    xf[pt] = *(const bf16x8*)(X + (pt * 16 + lrow) * 136 + quad * 8);

  #pragma unroll
  for (int ks = 0; ks < KSTEPS; ks++) {
    bf16x8 wn0, wn1, xn[4];
    if (ks + 1 < KSTEPS) {
      const int kn = (ks + 1) * 32 + quad * 8;
      wn0 = *(const bf16x8*)(W + (size_t)(c0 + lrow) * wstride + kn);
      wn1 = *(const bf16x8*)(W + (size_t)(c0 + 16 + lrow) * wstride + kn);
      #pragma unroll
      for (int pt = 0; pt < 4; pt++)
        xn[pt] = *(const bf16x8*)(X + (pt * 16 + lrow) * 136 + kn);
    }
    #pragma unroll
    for (int pt = 0; pt < 4; pt++) {
      acc[pt][0] = __builtin_amdgcn_mfma_f32_16x16x32_bf16(wf0, xf[pt], acc[pt][0], 0, 0, 0);
      acc[pt][1] = __builtin_amdgcn_mfma_f32_16x16x32_bf16(wf1, xf[pt], acc[pt][1], 0, 0, 0);
    }
    if (ks + 1 < KSTEPS) {
      wf0 = wn0; wf1 = wn1;
      #pragma unroll
      for (int pt = 0; pt < 4; pt++) xf[pt] = xn[pt];
    }
  }

  #pragma unroll
  for (int pt = 0; pt < 4; pt++) {
    #pragma unroll
    for (int wt = 0; wt < 2; wt++) {
      const int colg = c0 + wt * 16 + quad * 4;    // 4 consecutive out cols
      floatx4 s4 = *(const floatx4*)(sv + colg);
      floatx4 b4 = *(const floatx4*)(bv + colg);
      bf16x4 pk;
      #pragma unroll
      for (int r = 0; r < 4; r++) {
        float v = acc[pt][wt][r] * s4[r] + b4[r];
        pk[r] = (__bf16)(v > 0.f ? v : 0.f);
      }
      *(bf16x4*)(Y + (pt * 16 + lrow) * 136 + (colg - ycolbase)) = pk;
    }
  }
}

// ---------------------------------------------------------------------------
// MLP1: L0 reads B-fragments straight from f2t global with next-kstep
// register prefetch (gather latency overlapped with MFMA); posdiff enters
// via final k-step from registers. LDS = Y0+Y1 (34.8 KB) -> 4 blocks/CU.
// Vectorized bf16x8 maxpool epilogue.
// ---------------------------------------------------------------------------
__global__ __launch_bounds__(256, 4) void mlp1_kernel(
    const float* __restrict__ pos1, const float* __restrict__ pos2,
    const int* __restrict__ idx, const __bf16* __restrict__ f2t,
    const __bf16* __restrict__ w0p, const float* __restrict__ s10, const float* __restrict__ b10,
    const __bf16* __restrict__ w11b, const float* __restrict__ s11, const float* __restrict__ b11,
    const __bf16* __restrict__ w12b, const float* __restrict__ s12, const float* __restrict__ b12,
    __bf16* __restrict__ maxed)
{
  __shared__ __align__(16) __bf16 Y0[64 * 136];
  __shared__ __align__(16) __bf16 Y1[64 * 136];
  __shared__ int mrow[64];
  __shared__ __align__(16) float dp[64][4];

  const int b = blockIdx.y;
  const int n0 = blockIdx.x * 8;
  const int tid = threadIdx.x;
  const int wave = tid >> 6, lane = tid & 63;
  const int lrow = lane & 15, quad = lane >> 4;
  const int c0 = 32 * wave;

  // prologue: neighbor index + posdiff per row (row r = point g, rank k)
  if (tid < 64) {
    const int r = tid, g = r >> 3;
    const int m = idx[(b * N_ + n0) * K_ + r];
    mrow[r] = m;
    const int n = n0 + g;
    dp[r][0] = pos2[b * 3 * M_ + m]          - pos1[b * 3 * N_ + n];
    dp[r][1] = pos2[b * 3 * M_ + M_ + m]     - pos1[b * 3 * N_ + N_ + n];
    dp[r][2] = pos2[b * 3 * M_ + 2 * M_ + m] - pos1[b * 3 * N_ + 2 * N_ + n];
    dp[r][3] = 0.f;
  }
  __syncthreads();

  int mreg[4];
  #pragma unroll
  for (int pt = 0; pt < 4; pt++) mreg[pt] = mrow[pt * 16 + lrow];

  // last k-step fragment (posdiff) built in registers
  bf16x8 xlast[4];
  #pragma unroll
  for (int pt = 0; pt < 4; pt++) {
    bf16x8 v = {};
    if (quad == 0) {               // k=256..263: [dx,dy,dz,0,...]
      floatx4 d = *(const floatx4*)(&dp[pt * 16 + lrow][0]);
      v[0] = (__bf16)d[0]; v[1] = (__bf16)d[1]; v[2] = (__bf16)d[2];
    }
    xlast[pt] = v;                 // quads 1-3 zero (w0p zero-padded too)
  }

  // ---- L0: K=288 (8 ksteps from f2t + posdiff step). Out -> Y0.
  {
    floatx4 acc[4][2];
    const floatx4 fz = {0.f, 0.f, 0.f, 0.f};
    #pragma unroll
    for (int pt = 0; pt < 4; pt++) { acc[pt][0] = fz; acc[pt][1] = fz; }

    bf16x8 wf0 = *(const bf16x8*)(w0p + (size_t)(c0 + lrow) * 288 + quad * 8);
    bf16x8 wf1 = *(const bf16x8*)(w0p + (size_t)(c0 + 16 + lrow) * 288 + quad * 8);
    bf16x8 xf[4];
    #pragma unroll
    for (int pt = 0; pt < 4; pt++)
      xf[pt] = *(const bf16x8*)(f2t + ((size_t)(b * M_ + mreg[pt])) * 256 + quad * 8);

    #pragma unroll
    for (int ks = 0; ks < 9; ks++) {
      bf16x8 wn0, wn1, xn[4];
      if (ks < 8) {
        const int kn = (ks + 1) * 32 + quad * 8;
        wn0 = *(const bf16x8*)(w0p + (size_t)(c0 + lrow) * 288 + kn);
        wn1 = *(const bf16x8*)(w0p + (size_t)(c0 + 16 + lrow) * 288 + kn);
        if (ks < 7) {
          #pragma unroll
          for (int pt = 0; pt < 4; pt++)
            xn[pt] = *(const bf16x8*)(f2t + ((size_t)(b * M_ + mreg[pt])) * 256 + kn);
        } else {
          #pragma unroll
          for (int pt = 0; pt < 4; pt++) xn[pt] = xlast[pt];
        }
      }
      #pragma unroll
      for (int pt = 0; pt < 4; pt++) {
        acc[pt][0] = __builtin_amdgcn_mfma_f32_16x16x32_bf16(wf0, xf[pt], acc[pt][0], 0, 0, 0);
        acc[pt][1] = __builtin_amdgcn_mfma_f32_16x16x32_bf16(wf1, xf[pt], acc[pt][1], 0, 0, 0);
      }
      if (ks < 8) {
        wf0 = wn0; wf1 = wn1;
        #pragma unroll
        for (int pt = 0; pt < 4; pt++) xf[pt] = xn[pt];
      }
    }
    #pragma unroll
    for (int pt = 0; pt < 4; pt++) {
      #pragma unroll
      for (int wt = 0; wt < 2; wt++) {
        const int colg = c0 + wt * 16 + quad * 4;
        floatx4 s4 = *(const floatx4*)(s10 + colg);
        floatx4 b4 = *(const floatx4*)(b10 + colg);
        bf16x4 pk;
        #pragma unroll
        for (int r = 0; r < 4; r++) {
          float v = acc[pt][wt][r] * s4[r] + b4[r];
          pk[r] = (__bf16)(v > 0.f ? v : 0.f);
        }
        *(bf16x4*)(Y0 + (pt * 16 + lrow) * 136 + colg) = pk;
      }
    }
  }
  __syncthreads();

  // ---- L1: 128 -> 128, Y0 -> Y1
  mfma_layer_lds<4>(Y0, w11b, 128, s11, b11, Y1, 0, c0, lane);
  __syncthreads();

  // ---- L2: 128 -> 256 in two 128-col passes (out aliases Y0), maxpool K=8
  #pragma unroll
  for (int p = 0; p < 2; p++) {
    mfma_layer_lds<4>(Y1, w12b, 128, s12, b12, Y0, 128 * p, 128 * p + c0, lane);
    __syncthreads();
    // vectorized maxpool: 128 threads x 8 cols, b128 LDS reads + 16B store
    if (tid < 128) {
      const int g = tid >> 4, cb = (tid & 15) * 8;
      bf16x8 v0 = *(const bf16x8*)(Y0 + (g * 8) * 136 + cb);
      float fmx[8];
      #pragma unroll
      for (int j = 0; j < 8; j++) fmx[j] = (float)v0[j];
      #pragma unroll
      for (int k = 1; k < 8; k++) {
        bf16x8 v = *(const bf16x8*)(Y0 + (g * 8 + k) * 136 + cb);
        #pragma unroll
        for (int j = 0; j < 8; j++) {
          float f = (float)v[j];
          fmx[j] = f > fmx[j] ? f : fmx[j];
        }
      }
      bf16x8 o;
      #pragma unroll
      for (int j = 0; j < 8; j++) o[j] = (__bf16)fmx[j];
      *(bf16x8*)(maxed + ((size_t)(b * N_ + n0 + g)) * 256 + 128 * p + cb) = o;
    }
    __syncthreads();
  }
}

// ---------------------------------------------------------------------------
// MLP2: 32 rows x 128 out-cols per block, grid (1024, 2) = 2048 blocks
// (was 256 -> 1 block/CU, latency-bound). A = [maxed|f1t] bf16 contiguous,
// B = w20b [256][512]. Next-kstep register prefetch. Out fp32 floatx4.
// ---------------------------------------------------------------------------
__global__ __launch_bounds__(256, 6) void mlp2_kernel(
    const __bf16* __restrict__ maxed, const __bf16* __restrict__ f1t,
    const __bf16* __restrict__ w20b, const float* __restrict__ s20,
    const float* __restrict__ b20, float* __restrict__ out)
{
  const int rows0 = blockIdx.x * 32;           // b*N + n
  const int b = rows0 >> 13;
  const int nbase = rows0 & (N_ - 1);
  const int tid = threadIdx.x;
  const int wave = tid >> 6, lane = tid & 63;
  const int lrow = lane & 15, quad = lane >> 4;
  const int c0 = 128 * blockIdx.y + 32 * wave;
  const floatx4 fz = {0.f, 0.f, 0.f, 0.f};

  floatx4 acc[2][2];
  acc[0][0] = fz; acc[0][1] = fz; acc[1][0] = fz; acc[1][1] = fz;

  auto aptr = [&](int ks, int mt) -> const __bf16* {
    const int k = ks * 32 + quad * 8;
    return (ks < 8) ? (maxed + (size_t)(rows0 + mt * 16 + lrow) * 256 + k)
                    : (f1t + (size_t)(rows0 + mt * 16 + lrow) * 256 + (k - 256));
  };

  bf16x8 w0 = *(const bf16x8*)(w20b + (size_t)(c0 + lrow) * 512 + quad * 8);
  bf16x8 w1 = *(const bf16x8*)(w20b + (size_t)(c0 + 16 + lrow) * 512 + quad * 8);
  bf16x8 a0 = *(const bf16x8*)aptr(0, 0);
  bf16x8 a1 = *(const bf16x8*)aptr(0, 1);

  #pragma unroll
  for (int ks = 0; ks < 16; ks++) {
    bf16x8 wn0, wn1, an0, an1;
    if (ks < 15) {
      const int kn = (ks + 1) * 32 + quad * 8;
      wn0 = *(const bf16x8*)(w20b + (size_t)(c0 + lrow) * 512 + kn);
      wn1 = *(const bf16x8*)(w20b + (size_t)(c0 + 16 + lrow) * 512 + kn);
      an0 = *(const bf16x8*)aptr(ks + 1, 0);
      an1 = *(const bf16x8*)aptr(ks + 1, 1);
    }
    acc[0][0] = __builtin_amdgcn_mfma_f32_16x16x32_bf16(a0, w0, acc[0][0], 0, 0, 0);
    acc[0][1] = __builtin_amdgcn_mfma_f32_16x16x32_bf16(a0, w1, acc[0][1], 0, 0, 0);
    acc[1][0] = __builtin_amdgcn_mfma_f32_16x16x32_bf16(a1, w0, acc[1][0], 0, 0, 0);
    acc[1][1] = __builtin_amdgcn_mfma_f32_16x16x32_bf16(a1, w1, acc[1][1], 0, 0, 0);
    if (ks < 15) { w0 = wn0; w1 = wn1; a0 = an0; a1 = an1; }
  }

  #pragma unroll
  for (int ct = 0; ct < 2; ct++) {
    const int col = c0 + ct * 16 + lrow;
    const float s = s20[col];
    const float bb = b20[col];
    #pragma unroll
    for (int mt = 0; mt < 2; mt++) {
      floatx4 pk;
      #pragma unroll
      for (int r = 0; r < 4; r++) {
        float v = acc[mt][ct][r] * s + bb;
        pk[r] = v > 0.f ? v : 0.f;
      }
      const int n = nbase + mt * 16 + quad * 4;
      *(floatx4*)(out + ((size_t)(b * 256 + col)) * N_ + n) = pk;
    }
  }
}

// ---------------------------------------------------------------------------
extern "C" void kernel_launch(void* const* d_in, const int* in_sizes, int n_in,
                              void* d_out, int out_size, void* d_ws, size_t ws_size,
                              hipStream_t stream)
{
  const float* pos1     = (const float*)d_in[0];
  const float* pos2     = (const float*)d_in[1];
  const float* feature1 = (const float*)d_in[2];
  const float* feature2 = (const float*)d_in[3];
  const float* w1_0 = (const float*)d_in[4];
  const float* s1_0 = (const float*)d_in[5];
  const float* b1_0 = (const float*)d_in[6];
  const float* w1_1 = (const float*)d_in[7];
  const float* s1_1 = (const float*)d_in[8];
  const float* b1_1 = (const float*)d_in[9];
  const float* w1_2 = (const float*)d_in[10];
  const float* s1_2 = (const float*)d_in[11];
  const float* b1_2 = (const float*)d_in[12];
  const float* w2_0 = (const float*)d_in[13];
  const float* s2_0 = (const float*)d_in[14];
  const float* b2_0 = (const float*)d_in[15];

  // Workspace layout (39,231,488 B total)
  char* ws = (char*)d_ws;
  int*    idx   = (int*)(ws);                    //  1,048,576 @ 0
  __bf16* f2t   = (__bf16*)(ws + 1048576);       //  4,194,304
  __bf16* f1t   = (__bf16*)(ws + 5242880);       // 16,777,216
  __bf16* maxed = (__bf16*)(ws + 22020096);      // 16,777,216
  __bf16* w0p   = (__bf16*)(ws + 38797312);      //     73,728
  __bf16* w11b  = (__bf16*)(ws + 38871040);      //     32,768
  __bf16* w12b  = (__bf16*)(ws + 38903808);      //     65,536
  __bf16* w20b  = (__bf16*)(ws + 38969344);      //    262,144

  prep_weights<<<dim3(848), 256, 0, stream>>>(w1_0, w1_1, w1_2, w2_0,
                                              w0p, w11b, w12b, w20b);
  transpose_cast<<<dim3(M_ / 32, 8, B_), 256, 0, stream>>>(feature2, f2t, 256, M_);
  transpose_cast<<<dim3(N_ / 32, 8, B_), 256, 0, stream>>>(feature1, f1t, 256, N_);
  knn_kernel<<<dim3(N_ / 64, B_), 256, 0, stream>>>(pos1, pos2, idx);
  mlp1_kernel<<<dim3(N_ / 8, B_), 256, 0, stream>>>(
      pos1, pos2, idx, f2t, w0p, s1_0, b1_0, w11b, s1_1, b1_1, w12b, s1_2, b1_2, maxed);
  mlp2_kernel<<<dim3(1024, 2), 256, 0, stream>>>(maxed, f1t, w20b, s2_0, b2_0,
                                                 (float*)d_out);
}